// Round 4
// baseline (107.755 us; speedup 1.0000x reference)
//
#include <hip/hip_runtime.h>

// Problem constants
#define NLAYER 4
#define BB 4
#define LL 512
#define DD 768
#define NLIN 128
#define NENT 10

// Native vector type for nontemporal builtins (HIP_vector_type is rejected)
typedef float vfloat4 __attribute__((ext_vector_type(4)));

// Workspace layout (in floats):
//   weff   : [20][768] at offset 0        c-major; c<10: w_i-effective, c>=10: w_j-effective
//   constc : [16]      at offset 15360
//   si     : [40][512] at offset 15376    (constc folded in)
//   sj     : [40][512] at offset 35856
#define OFF_CONST 15360
#define OFF_SI    15376
#define OFF_SJ    35856

// ---------------------------------------------------------------------------
// Kernel A: fuse w_cls through w_span -> weff[20][768] (c-major), + constc.
// ---------------------------------------------------------------------------
__global__ void __launch_bounds__(256) fuse_weights(
    const float* __restrict__ w_span,
    const float* __restrict__ b_span,
    const float* __restrict__ w_cls,
    const float* __restrict__ b_cls,
    float* __restrict__ ws)
{
    int t = blockIdx.x * 256 + threadIdx.x;   // 0 .. 15359
    float* weff   = ws;
    float* constc = ws + OFF_CONST;

    if (t < 20 * DD) {
        int c2 = t / DD;
        int d  = t - c2 * DD;     // consecutive across lanes -> coalesced w_span reads
        int ci   = (c2 < NENT) ? c2 : c2 - NENT;
        int half = (c2 < NENT) ? 0  : 1;
        const float* wc    = w_cls + ci * NLIN;          // wave-uniform -> scalar loads
        const float* wsrow = w_span + half * DD + d;
        float acc = 0.f;
        #pragma unroll 8
        for (int o = 0; o < NLIN; ++o)
            acc += wc[o] * wsrow[(size_t)o * (2 * DD)];
        weff[c2 * DD + d] = acc;                          // c-major, coalesced
    }
    if (t < NENT) {
        float cc = b_cls[t];
        const float* wc = w_cls + t * NLIN;
        for (int o = 0; o < NLIN; ++o) cc += b_span[o] * wc[o];
        constc[t] = cc;
    }
}

// ---------------------------------------------------------------------------
// Kernel B: tok = sum over 4 layers; si/sj = tok @ weff^T.
// One wave per (b,l) row. hs prefetched into registers BEFORE the LDS
// staging so the hs loads and staging loads are in flight concurrently
// (barrier vmcnt(0) drains both at once). hs via nontemporal loads
// (read-once stream -- keep L2 for weff/si/sj).
// ---------------------------------------------------------------------------
__global__ void __launch_bounds__(256) reduce_proj(
    const float* __restrict__ hs,
    const float* __restrict__ wsro,
    float* __restrict__ si,
    float* __restrict__ sj)
{
    __shared__ float wsh[20 * DD];   // 61440 B -> 2 blocks/CU

    const int wave = (blockIdx.x * 256 + threadIdx.x) >> 6;  // 0..2047
    const int lane = threadIdx.x & 63;
    const int b = wave >> 9;
    const int l = wave & 511;

    const size_t LAYER_STRIDE = (size_t)BB * LL * DD;   // 1,572,864
    const size_t base = (size_t)(b * LL + l) * DD;

    // ---- register prefetch of hs: 3 chunks x 4 layers (48 VGPRs) ----
    vfloat4 t0[3], t1[3], t2[3], t3[3];
    #pragma unroll
    for (int k = 0; k < 3; ++k) {
        const int d0 = k * 256 + lane * 4;               // 16B-aligned, coalesced
        const vfloat4* hp = (const vfloat4*)(hs + base + d0);
        t0[k] = __builtin_nontemporal_load(hp);
        t1[k] = __builtin_nontemporal_load(hp + LAYER_STRIDE / 4);
        t2[k] = __builtin_nontemporal_load(hp + 2 * (LAYER_STRIDE / 4));
        t3[k] = __builtin_nontemporal_load(hp + 3 * (LAYER_STRIDE / 4));
    }

    // ---- cooperative LDS stage of weff: 3840 float4 / 256 threads ----
    {
        const vfloat4* src = (const vfloat4*)wsro;
        vfloat4*       dst = (vfloat4*)wsh;
        #pragma unroll
        for (int r = 0; r < 15; ++r)
            dst[r * 256 + threadIdx.x] = src[r * 256 + threadIdx.x];
    }
    __syncthreads();

    float acc[20];
    #pragma unroll
    for (int c = 0; c < 20; ++c) acc[c] = 0.f;

    #pragma unroll
    for (int k = 0; k < 3; ++k) {
        const int d0 = k * 256 + lane * 4;
        vfloat4 tv = t0[k] + t1[k] + t2[k] + t3[k];
        const float* wbase = wsh + d0;                   // + c*768 per channel
        #pragma unroll
        for (int c = 0; c < 20; ++c) {
            vfloat4 w = *(const vfloat4*)(wbase + c * DD); // ds_read_b128, conflict-free
            acc[c] += tv.x * w.x + tv.y * w.y + tv.z * w.z + tv.w * w.w;
        }
    }

    // Butterfly reduce each of the 20 partials across the wave
    #pragma unroll
    for (int c = 0; c < 20; ++c) {
        float v = acc[c];
        v += __shfl_xor(v, 1,  64);
        v += __shfl_xor(v, 2,  64);
        v += __shfl_xor(v, 4,  64);
        v += __shfl_xor(v, 8,  64);
        v += __shfl_xor(v, 16, 64);
        v += __shfl_xor(v, 32, 64);
        acc[c] = v;
    }

    if (lane == 0) {
        const float* constc = wsro + OFF_CONST;
        const int rb = b * NENT;
        #pragma unroll
        for (int c = 0; c < NENT; ++c) {
            si[(rb + c) * LL + l] = acc[c] + constc[c];
            sj[(rb + c) * LL + l] = acc[10 + c];
        }
    }
}

// ---------------------------------------------------------------------------
// Kernel C: out[b][c][i][j] = si[b*10+c][i] + sj[b*10+c][j]
// Nontemporal float4 stores (write-once, never re-read).
// ---------------------------------------------------------------------------
__global__ void __launch_bounds__(256) fill_out(
    const float* __restrict__ si,
    const float* __restrict__ sj,
    float* __restrict__ out)
{
    const int idx4 = blockIdx.x * 256 + threadIdx.x;     // exact grid
    const int j4 = idx4 & 127;          // j/4
    const int i  = (idx4 >> 7) & 511;
    const int bc = idx4 >> 16;          // b*10+c
    const float   s = si[bc * LL + i];
    const vfloat4 v = ((const vfloat4*)(sj + bc * LL))[j4];
    vfloat4 o = v + s;
    __builtin_nontemporal_store(o, (vfloat4*)out + idx4);
}

extern "C" void kernel_launch(void* const* d_in, const int* in_sizes, int n_in,
                              void* d_out, int out_size, void* d_ws, size_t ws_size,
                              hipStream_t stream) {
    const float* hs     = (const float*)d_in[0];  // (4,4,512,768)
    const float* w_span = (const float*)d_in[1];  // (128,1536)
    const float* b_span = (const float*)d_in[2];  // (128,)
    const float* w_cls  = (const float*)d_in[3];  // (10,128)
    const float* b_cls  = (const float*)d_in[4];  // (10,)
    float* ws  = (float*)d_ws;
    float* out = (float*)d_out;
    float* si = ws + OFF_SI;
    float* sj = ws + OFF_SJ;

    fuse_weights<<<60, 256, 0, stream>>>(w_span, b_span, w_cls, b_cls, ws);
    reduce_proj<<<512, 256, 0, stream>>>(hs, ws, si, sj);
    fill_out<<<10240, 256, 0, stream>>>(si, sj, out);
}

// Round 6
// 104.823 us; speedup vs baseline: 1.0280x; 1.0280x over previous
//
#include <hip/hip_runtime.h>

// Problem constants
#define NLAYER 4
#define BB 4
#define LL 512
#define DD 768
#define NLIN 128
#define NENT 10

// Workspace layout (in floats):
//   weff   : [20][768] at offset 0        c-major! c<10: w_i-effective, c>=10: w_j-effective
//   constc : [16]      at offset 15360    (b_span . w_cls[c] + b_cls[c])
//   si     : [40][512] at offset 15376    (si[b*10+c][i], constc folded in)
//   sj     : [40][512] at offset 35856
#define OFF_CONST 15360
#define OFF_SI    15376
#define OFF_SJ    35856

// ---------------------------------------------------------------------------
// Kernel A: fuse w_cls through w_span -> weff[20][768] (c-major), + constc.
// weff[c][d]      = sum_o w_cls[c][o] * w_span[o][d]        (c in 0..9)
// weff[10+c][d]   = sum_o w_cls[c][o] * w_span[o][768 + d]
// ---------------------------------------------------------------------------
__global__ void __launch_bounds__(256) fuse_weights(
    const float* __restrict__ w_span,
    const float* __restrict__ b_span,
    const float* __restrict__ w_cls,
    const float* __restrict__ b_cls,
    float* __restrict__ ws)
{
    int t = blockIdx.x * 256 + threadIdx.x;   // 0 .. 15359
    float* weff   = ws;
    float* constc = ws + OFF_CONST;

    if (t < 20 * DD) {
        int c2 = t / DD;          // 0..19
        int d  = t - c2 * DD;     // consecutive across lanes -> coalesced w_span reads
        int ci   = (c2 < NENT) ? c2 : c2 - NENT;
        int half = (c2 < NENT) ? 0  : 1;
        const float* wc    = w_cls + ci * NLIN;          // wave-uniform -> scalar loads
        const float* wsrow = w_span + half * DD + d;
        float acc = 0.f;
        #pragma unroll 8
        for (int o = 0; o < NLIN; ++o)
            acc += wc[o] * wsrow[(size_t)o * (2 * DD)];
        weff[c2 * DD + d] = acc;                          // c-major, coalesced store
    }
    if (t < NENT) {
        float cc = b_cls[t];
        const float* wc = w_cls + t * NLIN;
        for (int o = 0; o < NLIN; ++o) cc += b_span[o] * wc[o];
        constc[t] = cc;
    }
}

// ---------------------------------------------------------------------------
// Kernel B: tok = sum over 4 layers; si/sj = tok @ weff^T.
// One wave per (b,l) row: 2048 rows = 512 blocks x 4 waves.
// Weights staged in LDS, c-major: lane reads weff[c][k*256+4*lane .. +3] as
// one ds_read_b128 -- 64 lanes x 16 B contiguous = conflict-free.
// ---------------------------------------------------------------------------
__global__ void __launch_bounds__(256) reduce_proj(
    const float* __restrict__ hs,
    const float* __restrict__ wsro,
    float* __restrict__ si,
    float* __restrict__ sj)
{
    __shared__ float wsh[20 * DD];   // 61440 B -> 2 blocks/CU

    // Cooperative stage: 15360 floats = 3840 float4 / 256 threads = 15 each.
    {
        const float4* src = (const float4*)wsro;
        float4*       dst = (float4*)wsh;
        #pragma unroll
        for (int r = 0; r < 15; ++r)
            dst[r * 256 + threadIdx.x] = src[r * 256 + threadIdx.x];
    }
    __syncthreads();

    const int wave = (blockIdx.x * 256 + threadIdx.x) >> 6;  // 0..2047
    const int lane = threadIdx.x & 63;
    const int b = wave >> 9;
    const int l = wave & 511;

    const size_t LAYER_STRIDE = (size_t)BB * LL * DD;   // 1,572,864
    const size_t base = (size_t)(b * LL + l) * DD;

    float acc[20];
    #pragma unroll
    for (int c = 0; c < 20; ++c) acc[c] = 0.f;

    #pragma unroll
    for (int k = 0; k < 3; ++k) {
        const int d0 = k * 256 + lane * 4;               // 16B-aligned, coalesced
        const float* hp = hs + base + d0;
        float4 t0 = *(const float4*)(hp);
        float4 t1 = *(const float4*)(hp + LAYER_STRIDE);
        float4 t2 = *(const float4*)(hp + 2 * LAYER_STRIDE);
        float4 t3 = *(const float4*)(hp + 3 * LAYER_STRIDE);
        float4 tv;
        tv.x = t0.x + t1.x + t2.x + t3.x;
        tv.y = t0.y + t1.y + t2.y + t3.y;
        tv.z = t0.z + t1.z + t2.z + t3.z;
        tv.w = t0.w + t1.w + t2.w + t3.w;
        const float* wbase = wsh + d0;                   // + c*768 per channel
        #pragma unroll
        for (int c = 0; c < 20; ++c) {
            float4 w = *(const float4*)(wbase + c * DD); // ds_read_b128, conflict-free
            acc[c] += tv.x * w.x + tv.y * w.y + tv.z * w.z + tv.w * w.w;
        }
    }

    // Butterfly reduce each of the 20 partials across the wave (64 lanes)
    #pragma unroll
    for (int c = 0; c < 20; ++c) {
        float v = acc[c];
        v += __shfl_xor(v, 1,  64);
        v += __shfl_xor(v, 2,  64);
        v += __shfl_xor(v, 4,  64);
        v += __shfl_xor(v, 8,  64);
        v += __shfl_xor(v, 16, 64);
        v += __shfl_xor(v, 32, 64);
        acc[c] = v;
    }

    if (lane == 0) {
        const float* constc = wsro + OFF_CONST;
        const int rb = b * NENT;
        #pragma unroll
        for (int c = 0; c < NENT; ++c) {
            si[(rb + c) * LL + l] = acc[c] + constc[c];   // fold const into si
            sj[(rb + c) * LL + l] = acc[10 + c];
        }
    }
}

// ---------------------------------------------------------------------------
// Kernel C: out[b][c][i][j] = si[b*10+c][i] + sj[b*10+c][j]
// float4 over j. Total float4 elements = 40*512*512/4 = 2,621,440.
// ---------------------------------------------------------------------------
__global__ void __launch_bounds__(256) fill_out(
    const float* __restrict__ si,
    const float* __restrict__ sj,
    float* __restrict__ out)
{
    const int idx4 = blockIdx.x * 256 + threadIdx.x;     // exact grid, no bounds check
    const int j4 = idx4 & 127;          // j/4
    const int i  = (idx4 >> 7) & 511;
    const int bc = idx4 >> 16;          // b*10+c, 0..39
    const float  s  = si[bc * LL + i];
    const float4 v  = ((const float4*)(sj + bc * LL))[j4];
    float4 o;
    o.x = s + v.x; o.y = s + v.y; o.z = s + v.z; o.w = s + v.w;
    ((float4*)out)[idx4] = o;
}

extern "C" void kernel_launch(void* const* d_in, const int* in_sizes, int n_in,
                              void* d_out, int out_size, void* d_ws, size_t ws_size,
                              hipStream_t stream) {
    const float* hs     = (const float*)d_in[0];  // (4,4,512,768)
    const float* w_span = (const float*)d_in[1];  // (128,1536)
    const float* b_span = (const float*)d_in[2];  // (128,)
    const float* w_cls  = (const float*)d_in[3];  // (10,128)
    const float* b_cls  = (const float*)d_in[4];  // (10,)
    float* ws  = (float*)d_ws;
    float* out = (float*)d_out;
    float* si = ws + OFF_SI;
    float* sj = ws + OFF_SJ;

    fuse_weights<<<60, 256, 0, stream>>>(w_span, b_span, w_cls, b_cls, ws);
    reduce_proj<<<512, 256, 0, stream>>>(hs, ws, si, sj);
    // 2,621,440 float4 elements / 256 = 10240 blocks, exact
    fill_out<<<10240, 256, 0, stream>>>(si, sj, out);
}